// Round 5
// baseline (5835.699 us; speedup 1.0000x reference)
//
#include <hip/hip_runtime.h>
#include <hip/hip_bf16.h>
#include <hip/hip_cooperative_groups.h>
#include <math.h>

namespace cg = cooperative_groups;

#define B_   128
#define P_   196
#define ENC_ 2048
#define A_   512
#define H_   512
#define E_   512
#define V_   10000
#define T_   20
#define NDF_ 2560   /* fused att2(512) + fbeta(2048) */
#define XK_  3072   /* gates K: E + ENC + H */

typedef __attribute__((ext_vector_type(8))) short bf16x8;
typedef __attribute__((ext_vector_type(4))) short bf16x4;
typedef __attribute__((ext_vector_type(4))) float f32x4;

__device__ __forceinline__ float sigmoidf_(float x) { return 1.0f / (1.0f + expf(-x)); }

__device__ __forceinline__ short f2bf(float f) {
    unsigned u = __float_as_uint(f);
    u += 0x7fffu + ((u >> 16) & 1u);
    return (short)(u >> 16);
}
__device__ __forceinline__ float bf2f(short s) {
    return __uint_as_float(((unsigned)(unsigned short)s) << 16);
}
__device__ __forceinline__ void gload_lds16(const void* g, void* l) {
    __builtin_amdgcn_global_load_lds(
        (const __attribute__((address_space(1))) void*)g,
        (__attribute__((address_space(3))) void*)l, 16, 0, 0);
}

#define BM 128
#define BN 64
#define BK 64

// shared MFMA inner compute: 64-K slab from As/Bs (XOR-swizzled layout)
#define COMPUTE64(ASP, BSP, CUR)                                               \
    _Pragma("unroll")                                                          \
    for (int kk = 0; kk < BK; kk += 32) {                                      \
        const int kb = (kk >> 3) + (lane >> 4);                                \
        bf16x8 av[4], bv[2];                                                   \
        _Pragma("unroll")                                                      \
        for (int i = 0; i < 4; i++) {                                          \
            int rr = wr * 64 + i * 16 + (lane & 15);                           \
            av[i] = *(const bf16x8*)&(ASP)[(CUR) * (BM * BK) + rr * BK         \
                    + ((kb ^ (rr & 7)) << 3)];                                 \
        }                                                                      \
        _Pragma("unroll")                                                      \
        for (int j = 0; j < 2; j++) {                                          \
            int cc = wc * 32 + j * 16 + (lane & 15);                           \
            bv[j] = *(const bf16x8*)&(BSP)[(CUR) * (BN * BK) + cc * BK         \
                    + ((kb ^ (cc & 7)) << 3)];                                 \
        }                                                                      \
        _Pragma("unroll")                                                      \
        for (int i = 0; i < 4; i++)                                            \
            _Pragma("unroll")                                                  \
            for (int j = 0; j < 2; j++)                                        \
                acc[i][j] = __builtin_amdgcn_mfma_f32_16x16x32_bf16(           \
                    av[i], bv[j], acc[i][j], 0, 0, 0);                         \
    }

// ---------------------------------------------------------------------------
// Generic GEMM (standalone): C[M,N] = A_bf16[M,K] @ B_bf16[N,K]^T + bias[N]
// Used for att1 / init / pred. pred mode: row r=(t*128+b) -> out[b][t][:], masked.
// ---------------------------------------------------------------------------
__global__ __launch_bounds__(256) void gemm_bf(
    const short* __restrict__ A, const short* __restrict__ Bw,
    float* __restrict__ Cf, short* __restrict__ Cb,
    const float* __restrict__ bias,
    int N, int K, int lda, int ldb, int ldc,
    int mtiles, int ntiles, int pred,
    const int* __restrict__ lengths)
{
    __shared__ __attribute__((aligned(16))) short As[2][BM * BK];
    __shared__ __attribute__((aligned(16))) short Bs[2][BN * BK];
    int pm, pn;
    if (mtiles == 1) { pm = 0; pn = blockIdx.x; }
    else {
        int xcd = blockIdx.x & 7, s = blockIdx.x >> 3;
        pn = s % ntiles;
        pm = (s / ntiles) * 8 + xcd;
        if (pm >= mtiles) return;
    }
    const int bm = pm * BM, bn = pn * BN;
    const int tid = threadIdx.x, w = tid >> 6, lane = tid & 63;
    const int wr = w >> 1, wc = w & 1;
    const int lr8 = lane >> 3, lk = lane & 7;

    f32x4 zero4 = {0.f, 0.f, 0.f, 0.f};
    f32x4 acc[4][2];
    #pragma unroll
    for (int i = 0; i < 4; i++)
        #pragma unroll
        for (int j = 0; j < 2; j++) acc[i][j] = zero4;

#define STAGE(buf, k0) {                                                        \
    _Pragma("unroll")                                                           \
    for (int i = 0; i < 4; i++) {                                               \
        int row0 = w * 32 + i * 8; int row = row0 + lr8;                        \
        gload_lds16(A + (size_t)(bm + row) * lda + (k0)                         \
                    + ((lk ^ (row & 7)) << 3), &As[buf][row0 * BK]);            \
    }                                                                           \
    _Pragma("unroll")                                                           \
    for (int i = 0; i < 2; i++) {                                               \
        int row0 = w * 16 + i * 8; int row = row0 + lr8;                        \
        int gn = bn + row; if (gn > N - 1) gn = N - 1;                          \
        gload_lds16(Bw + (size_t)gn * ldb + (k0)                                \
                    + ((lk ^ (row & 7)) << 3), &Bs[buf][row0 * BK]);            \
    } }

    STAGE(0, 0);
    __syncthreads();
    int cur = 0;
    for (int k0 = 0; k0 < K; k0 += BK) {
        if (k0 + BK < K) STAGE(cur ^ 1, k0 + BK);
        COMPUTE64(&As[0][0], &Bs[0][0], cur);
        __syncthreads();
        cur ^= 1;
    }
#undef STAGE

    const int lr = lane >> 4, lc = lane & 15;
    #pragma unroll
    for (int i = 0; i < 4; i++) {
        #pragma unroll
        for (int r = 0; r < 4; r++) {
            int row = bm + wr * 64 + i * 16 + lr * 4 + r;
            #pragma unroll
            for (int j = 0; j < 2; j++) {
                int col = bn + wc * 32 + j * 16 + lc;
                if (col >= N) continue;
                float v = acc[i][j][r] + bias[col];
                if (pred) {
                    int tt = row >> 7, bb = row & 127;
                    float rs = (tt < lengths[bb] - 1) ? 1.0f : 0.0f;
                    Cf[(size_t)bb * T_ * V_ + (size_t)tt * V_ + col] = v * rs;
                } else if (Cb) {
                    Cb[(size_t)row * ldc + col] = f2bf(v);
                } else {
                    Cf[(size_t)row * ldc + col] = v;
                }
            }
        }
    }
}

// ---------------------------------------------------------------------------
// Cooperative persistent kernel: runs the entire T=20 recurrence.
// 256 blocks x 256 threads. Per step:
//   Phase A (blocks 0..39):  attf = h @ [W_dec|W_fbeta]^T + bdf  (MFMA)
//   Phase B (all 256):       e + softmax + context  (skip masked b)
//   Phase C (blocks 0..31):  gates GEMM (gate-interleaved W) + LSTM epilogue
// h is ping-ponged between steps (read h[t&1], write h[(t&1)^1]).
// ---------------------------------------------------------------------------
__global__ __launch_bounds__(256) void loop_kernel(
    const short* __restrict__ att1_bf, const short* __restrict__ enc_bf,
    const short* __restrict__ Wdf, const float* __restrict__ bdf,
    const float* __restrict__ wfull,
    const short* __restrict__ emb_all, const short* __restrict__ Wcat,
    const float* __restrict__ bcat,
    short* __restrict__ hbufs, float* __restrict__ cbuf,
    short* __restrict__ hn_all, float* __restrict__ attf,
    short* __restrict__ ctxbuf, const int* __restrict__ lengths)
{
    cg::grid_group grid = cg::this_grid();
    __shared__ __attribute__((aligned(16))) char smem[49152];
    const int blk = blockIdx.x;
    const int tid = threadIdx.x, w = tid >> 6, lane = tid & 63;
    const int wr = w >> 1, wc = w & 1;
    const int lr8 = lane >> 3, lk = lane & 7;
    const int lr = lane >> 4, lc = lane & 15;

    for (int t = 0; t < T_; t++) {
        short* hcur = hbufs + (size_t)(t & 1) * B_ * H_;
        short* hnxt = hbufs + (size_t)((t & 1) ^ 1) * B_ * H_;

        // ---------------- Phase A: attf [128 x 2560, K=512]
        if (blk < NDF_ / BN) {
            short* As0 = (short*)smem;
            short* Bs0 = (short*)(smem + 32768);
            const int bn = blk * BN;
            f32x4 zero4 = {0.f, 0.f, 0.f, 0.f};
            f32x4 acc[4][2];
            #pragma unroll
            for (int i = 0; i < 4; i++)
                #pragma unroll
                for (int j = 0; j < 2; j++) acc[i][j] = zero4;
#define STAGE_A(buf, k0) {                                                      \
    _Pragma("unroll")                                                           \
    for (int i = 0; i < 4; i++) {                                               \
        int row0 = w * 32 + i * 8; int row = row0 + lr8;                        \
        gload_lds16(hcur + (size_t)row * H_ + (k0)                              \
                    + ((lk ^ (row & 7)) << 3), &As0[(buf) * (BM*BK) + row0*BK]);\
    }                                                                           \
    _Pragma("unroll")                                                           \
    for (int i = 0; i < 2; i++) {                                               \
        int row0 = w * 16 + i * 8; int row = row0 + lr8;                        \
        gload_lds16(Wdf + (size_t)(bn + row) * H_ + (k0)                        \
                    + ((lk ^ (row & 7)) << 3), &Bs0[(buf) * (BN*BK) + row0*BK]);\
    } }
            STAGE_A(0, 0);
            __syncthreads();
            int cur = 0;
            for (int k0 = 0; k0 < H_; k0 += BK) {
                if (k0 + BK < H_) STAGE_A(cur ^ 1, k0 + BK);
                COMPUTE64(As0, Bs0, cur);
                __syncthreads();
                cur ^= 1;
            }
#undef STAGE_A
            #pragma unroll
            for (int i = 0; i < 4; i++)
                #pragma unroll
                for (int r = 0; r < 4; r++) {
                    int row = wr * 64 + i * 16 + lr * 4 + r;
                    #pragma unroll
                    for (int j = 0; j < 2; j++) {
                        int col = bn + wc * 32 + j * 16 + lc;
                        attf[(size_t)row * NDF_ + col] = acc[i][j][r] + bdf[col];
                    }
                }
        }
        __threadfence();
        grid.sync();
        __threadfence();

        // ---------------- Phase B: e + softmax + context (b = blk>>1, half = blk&1)
        {
            const int b = blk >> 1, half = blk & 1;
            if (t < lengths[b] - 1) {
                float* es  = (float*)smem;          // [256]
                float* red = (float*)smem + 256;    // [256]
                float* al  = (float*)smem + 512;    // [256]
                float* st  = (float*)smem + 768;    // [2]
                float a2v[8], wv8[8];
                const float* a2 = attf + (size_t)b * NDF_;
                #pragma unroll
                for (int i = 0; i < 8; i++) {
                    a2v[i] = a2[lane * 8 + i];
                    wv8[i] = wfull[lane * 8 + i];
                }
                for (int r = 0; r < 49; r++) {
                    int row = w * 49 + r;
                    bf16x8 a1 = *(const bf16x8*)(att1_bf + ((size_t)b * P_ + row) * A_ + lane * 8);
                    float s = 0.0f;
                    #pragma unroll
                    for (int i = 0; i < 8; i++) {
                        float v = bf2f(a1[i]) + a2v[i];
                        s += fmaxf(v, 0.0f) * wv8[i];
                    }
                    #pragma unroll
                    for (int off2 = 32; off2 > 0; off2 >>= 1) s += __shfl_down(s, off2, 64);
                    if (lane == 0) es[row] = s;
                }
                __syncthreads();
                float v = (tid < P_) ? es[tid] : -1e30f;
                red[tid] = v;
                __syncthreads();
                for (int rs = 128; rs > 0; rs >>= 1) {
                    if (tid < rs) red[tid] = fmaxf(red[tid], red[tid + rs]);
                    __syncthreads();
                }
                if (tid == 0) st[0] = red[0];
                __syncthreads();
                float ex = (tid < P_) ? expf(v - st[0]) : 0.0f;
                red[tid] = ex;
                __syncthreads();
                for (int rs = 128; rs > 0; rs >>= 1) {
                    if (tid < rs) red[tid] += red[tid + rs];
                    __syncthreads();
                }
                if (tid == 0) st[1] = red[0];
                __syncthreads();
                if (tid < P_) al[tid] = ex / st[1];
                __syncthreads();

                const int c0 = half * 1024 + tid * 4;
                const short* eb = enc_bf + (size_t)b * P_ * ENC_ + c0;
                float s0 = 0, s1 = 0, s2 = 0, s3 = 0;
                for (int p = 0; p < P_; p++) {
                    bf16x4 ev = *(const bf16x4*)(eb + (size_t)p * ENC_);
                    float a = al[p];
                    s0 += a * bf2f(ev[0]); s1 += a * bf2f(ev[1]);
                    s2 += a * bf2f(ev[2]); s3 += a * bf2f(ev[3]);
                }
                const float* fb = attf + (size_t)b * NDF_ + A_;
                short* xo = ctxbuf + (size_t)b * ENC_ + c0;
                xo[0] = f2bf(sigmoidf_(fb[c0 + 0]) * s0);
                xo[1] = f2bf(sigmoidf_(fb[c0 + 1]) * s1);
                xo[2] = f2bf(sigmoidf_(fb[c0 + 2]) * s2);
                xo[3] = f2bf(sigmoidf_(fb[c0 + 3]) * s3);
            }
        }
        __threadfence();
        grid.sync();
        __threadfence();

        // ---------------- Phase C: gates [128 x 2048, K=3072] + LSTM
        if (blk < (4 * H_) / BN) {
            short* As0 = (short*)smem;
            short* Bs0 = (short*)(smem + 32768);
            const short* embA = emb_all + (size_t)t * B_ * E_;
            short* hn_t = hn_all + (size_t)t * B_ * H_;
            const int bn = blk * BN;
            f32x4 zero4 = {0.f, 0.f, 0.f, 0.f};
            f32x4 acc[4][2];
            #pragma unroll
            for (int i = 0; i < 4; i++)
                #pragma unroll
                for (int j = 0; j < 2; j++) acc[i][j] = zero4;
#define STAGE_C(buf, k0) {                                                      \
    const short* Ap; int Al, kk0;                                               \
    if ((k0) < 512)       { Ap = embA;   Al = 512;  kk0 = (k0); }               \
    else if ((k0) < 2560) { Ap = ctxbuf; Al = 2048; kk0 = (k0) - 512; }         \
    else                  { Ap = hcur;   Al = 512;  kk0 = (k0) - 2560; }        \
    _Pragma("unroll")                                                           \
    for (int i = 0; i < 4; i++) {                                               \
        int row0 = w * 32 + i * 8; int row = row0 + lr8;                        \
        gload_lds16(Ap + (size_t)row * Al + kk0 + ((lk ^ (row & 7)) << 3),      \
                    &As0[(buf) * (BM * BK) + row0 * BK]);                       \
    }                                                                           \
    _Pragma("unroll")                                                           \
    for (int i = 0; i < 2; i++) {                                               \
        int row0 = w * 16 + i * 8; int row = row0 + lr8;                        \
        gload_lds16(Wcat + (size_t)(bn + row) * XK_ + (k0)                      \
                    + ((lk ^ (row & 7)) << 3),                                  \
                    &Bs0[(buf) * (BN * BK) + row0 * BK]);                       \
    } }
            STAGE_C(0, 0);
            __syncthreads();
            int cur = 0;
            for (int k0 = 0; k0 < XK_; k0 += BK) {
                if (k0 + BK < XK_) STAGE_C(cur ^ 1, k0 + BK);
                COMPUTE64(As0, Bs0, cur);
                __syncthreads();
                cur ^= 1;
            }
#undef STAGE_C
            float* gl = (float*)smem;     // 128*68*4 = 34816 B
            #pragma unroll
            for (int i = 0; i < 4; i++)
                #pragma unroll
                for (int r = 0; r < 4; r++) {
                    int row = wr * 64 + i * 16 + lr * 4 + r;
                    #pragma unroll
                    for (int j = 0; j < 2; j++) {
                        int col = wc * 32 + j * 16 + lc;
                        gl[row * 68 + col] = acc[i][j][r] + bcat[bn + col];
                    }
                }
            __syncthreads();
            #pragma unroll
            for (int q = 0; q < 8; q++) {
                int id  = tid * 8 + q;
                int row = id >> 4;
                int j   = id & 15;
                int jg  = (bn >> 2) + j;
                float i_ = sigmoidf_(gl[row * 68 + 4 * j + 0]);
                float f_ = sigmoidf_(gl[row * 68 + 4 * j + 1]);
                float g_ = tanhf    (gl[row * 68 + 4 * j + 2]);
                float o_ = sigmoidf_(gl[row * 68 + 4 * j + 3]);
                float cn = f_ * cbuf[row * H_ + jg] + i_ * g_;
                float hv = o_ * tanhf(cn);
                hn_t[row * H_ + jg] = f2bf(hv);
                bool m = t < lengths[row] - 1;
                if (m) cbuf[row * H_ + jg] = cn;
                hnxt[row * H_ + jg] = m ? f2bf(hv) : hcur[row * H_ + jg];
            }
        }
        __threadfence();
        grid.sync();
        __threadfence();
    }
}

// ---------------------------------------------------------------------------
// Fallback per-step kernels (used only if cooperative launch fails)
// ---------------------------------------------------------------------------
__global__ __launch_bounds__(256) void esmctx_kernel(
    const short* __restrict__ att1_bf, const float* __restrict__ attf,
    const float* __restrict__ wfull, const short* __restrict__ enc_bf,
    short* __restrict__ ctxbuf, const int* __restrict__ lengths, int t)
{
    __shared__ float es[P_];
    __shared__ float red[256];
    __shared__ float al[P_];
    __shared__ float sm, ss;
    const int b = blockIdx.y, half = blockIdx.x;
    if (t >= lengths[b] - 1) return;
    const int tid = threadIdx.x, wv = tid >> 6, lane = tid & 63;

    float a2v[8], wv8[8];
    const float* a2 = attf + (size_t)b * NDF_;
    #pragma unroll
    for (int i = 0; i < 8; i++) {
        a2v[i] = a2[lane * 8 + i];
        wv8[i] = wfull[lane * 8 + i];
    }
    for (int r = 0; r < 49; r++) {
        int row = wv * 49 + r;
        bf16x8 a1 = *(const bf16x8*)(att1_bf + ((size_t)b * P_ + row) * A_ + lane * 8);
        float s = 0.0f;
        #pragma unroll
        for (int i = 0; i < 8; i++) {
            float v = bf2f(a1[i]) + a2v[i];
            s += fmaxf(v, 0.0f) * wv8[i];
        }
        #pragma unroll
        for (int off = 32; off > 0; off >>= 1) s += __shfl_down(s, off, 64);
        if (lane == 0) es[row] = s;
    }
    __syncthreads();
    float v = (tid < P_) ? es[tid] : -1e30f;
    red[tid] = v;
    __syncthreads();
    for (int rs = 128; rs > 0; rs >>= 1) {
        if (tid < rs) red[tid] = fmaxf(red[tid], red[tid + rs]);
        __syncthreads();
    }
    if (tid == 0) sm = red[0];
    __syncthreads();
    float ex = (tid < P_) ? expf(v - sm) : 0.0f;
    red[tid] = ex;
    __syncthreads();
    for (int rs = 128; rs > 0; rs >>= 1) {
        if (tid < rs) red[tid] += red[tid + rs];
        __syncthreads();
    }
    if (tid == 0) ss = red[0];
    __syncthreads();
    if (tid < P_) al[tid] = ex / ss;
    __syncthreads();

    const int c0 = half * 1024 + tid * 4;
    const short* eb = enc_bf + (size_t)b * P_ * ENC_ + c0;
    float s0 = 0, s1 = 0, s2 = 0, s3 = 0;
    for (int p = 0; p < P_; p++) {
        bf16x4 ev = *(const bf16x4*)(eb + (size_t)p * ENC_);
        float a = al[p];
        s0 += a * bf2f(ev[0]); s1 += a * bf2f(ev[1]);
        s2 += a * bf2f(ev[2]); s3 += a * bf2f(ev[3]);
    }
    const float* fb = attf + (size_t)b * NDF_ + A_;
    short* xo = ctxbuf + (size_t)b * ENC_ + c0;
    xo[0] = f2bf(sigmoidf_(fb[c0 + 0]) * s0);
    xo[1] = f2bf(sigmoidf_(fb[c0 + 1]) * s1);
    xo[2] = f2bf(sigmoidf_(fb[c0 + 2]) * s2);
    xo[3] = f2bf(sigmoidf_(fb[c0 + 3]) * s3);
}

__global__ __launch_bounds__(256) void gates_lstm(
    const short* __restrict__ embA, const short* __restrict__ ctxbuf,
    const short* __restrict__ hcur, short* __restrict__ hnxt,
    const short* __restrict__ Wcat, const float* __restrict__ bcat,
    float* __restrict__ cbuf, short* __restrict__ hn_t,
    const int* __restrict__ lengths, int t)
{
    __shared__ __attribute__((aligned(16))) char smem[49152];
    short* As0 = (short*)smem;
    short* Bs0 = (short*)(smem + 32768);
    const int bn = blockIdx.x * BN;
    const int tid = threadIdx.x, w = tid >> 6, lane = tid & 63;
    const int wr = w >> 1, wc = w & 1;
    const int lr8 = lane >> 3, lk = lane & 7;

    f32x4 zero4 = {0.f, 0.f, 0.f, 0.f};
    f32x4 acc[4][2];
    #pragma unroll
    for (int i = 0; i < 4; i++)
        #pragma unroll
        for (int j = 0; j < 2; j++) acc[i][j] = zero4;

#define STAGE_G(buf, k0) {                                                      \
    const short* Ap; int Al, kk0;                                               \
    if ((k0) < 512)       { Ap = embA;   Al = 512;  kk0 = (k0); }               \
    else if ((k0) < 2560) { Ap = ctxbuf; Al = 2048; kk0 = (k0) - 512; }         \
    else                  { Ap = hcur;   Al = 512;  kk0 = (k0) - 2560; }        \
    _Pragma("unroll")                                                           \
    for (int i = 0; i < 4; i++) {                                               \
        int row0 = w * 32 + i * 8; int row = row0 + lr8;                        \
        gload_lds16(Ap + (size_t)row * Al + kk0 + ((lk ^ (row & 7)) << 3),      \
                    &As0[(buf) * (BM * BK) + row0 * BK]);                       \
    }                                                                           \
    _Pragma("unroll")                                                           \
    for (int i = 0; i < 2; i++) {                                               \
        int row0 = w * 16 + i * 8; int row = row0 + lr8;                        \
        gload_lds16(Wcat + (size_t)(bn + row) * XK_ + (k0)                      \
                    + ((lk ^ (row & 7)) << 3),                                  \
                    &Bs0[(buf) * (BN * BK) + row0 * BK]);                       \
    } }

    STAGE_G(0, 0);
    __syncthreads();
    int cur = 0;
    for (int k0 = 0; k0 < XK_; k0 += BK) {
        if (k0 + BK < XK_) STAGE_G(cur ^ 1, k0 + BK);
        COMPUTE64(As0, Bs0, cur);
        __syncthreads();
        cur ^= 1;
    }
#undef STAGE_G

    float* gl = (float*)smem;
    const int lr = lane >> 4, lc = lane & 15;
    #pragma unroll
    for (int i = 0; i < 4; i++)
        #pragma unroll
        for (int r = 0; r < 4; r++) {
            int row = wr * 64 + i * 16 + lr * 4 + r;
            #pragma unroll
            for (int j = 0; j < 2; j++) {
                int col = wc * 32 + j * 16 + lc;
                gl[row * 68 + col] = acc[i][j][r] + bcat[bn + col];
            }
        }
    __syncthreads();
    #pragma unroll
    for (int q = 0; q < 8; q++) {
        int id  = tid * 8 + q;
        int row = id >> 4;
        int j   = id & 15;
        int jg  = (bn >> 2) + j;
        float i_ = sigmoidf_(gl[row * 68 + 4 * j + 0]);
        float f_ = sigmoidf_(gl[row * 68 + 4 * j + 1]);
        float g_ = tanhf    (gl[row * 68 + 4 * j + 2]);
        float o_ = sigmoidf_(gl[row * 68 + 4 * j + 3]);
        float cn = f_ * cbuf[row * H_ + jg] + i_ * g_;
        float hv = o_ * tanhf(cn);
        hn_t[row * H_ + jg] = f2bf(hv);
        bool m = t < lengths[row] - 1;
        if (m) cbuf[row * H_ + jg] = cn;
        hnxt[row * H_ + jg] = m ? f2bf(hv) : hcur[row * H_ + jg];
    }
}

// ---- one-time prep kernels ------------------------------------------------

__global__ __launch_bounds__(256) void castenc(const float* __restrict__ in,
                                               short* __restrict__ out)
{
    size_t i8 = ((size_t)blockIdx.x * 256 + threadIdx.x) * 8;
    float4 f0 = *(const float4*)(in + i8);
    float4 f1 = *(const float4*)(in + i8 + 4);
    bf16x8 v;
    v[0] = f2bf(f0.x); v[1] = f2bf(f0.y); v[2] = f2bf(f0.z); v[3] = f2bf(f0.w);
    v[4] = f2bf(f1.x); v[5] = f2bf(f1.y); v[6] = f2bf(f1.z); v[7] = f2bf(f1.w);
    *(bf16x8*)(out + i8) = v;
}

__global__ __launch_bounds__(256) void castk(const float* __restrict__ in,
                                             short* __restrict__ out, int n)
{
    int i4 = (blockIdx.x * 256 + threadIdx.x) * 4;
    if (i4 >= n) return;
    float4 f = *(const float4*)(in + i4);
    out[i4 + 0] = f2bf(f.x); out[i4 + 1] = f2bf(f.y);
    out[i4 + 2] = f2bf(f.z); out[i4 + 3] = f2bf(f.w);
}

__global__ __launch_bounds__(256) void wdf_kernel(const float* __restrict__ W_dec,
                                                  const float* __restrict__ W_fbeta,
                                                  short* __restrict__ out)
{
    int k = blockIdx.x * 256 + threadIdx.x;
    int n = blockIdx.y;
    float v = (n < A_) ? W_dec[(size_t)n * H_ + k]
                       : W_fbeta[(size_t)(n - A_) * H_ + k];
    out[(size_t)n * H_ + k] = f2bf(v);
}

__global__ __launch_bounds__(256) void wcat_kernel(const float* __restrict__ W_ih,
                                                   const float* __restrict__ W_hh,
                                                   short* __restrict__ out)
{
    int k = blockIdx.x * 256 + threadIdx.x;
    int n = blockIdx.y;
    int srow = (n & 3) * H_ + (n >> 2);
    float v = (k < E_ + ENC_) ? W_ih[(size_t)srow * (E_ + ENC_) + k]
                              : W_hh[(size_t)srow * H_ + (k - (E_ + ENC_))];
    out[(size_t)n * XK_ + k] = f2bf(v);
}

__global__ __launch_bounds__(256) void bdf_kernel(const float* __restrict__ b_dec,
                                                  const float* __restrict__ b_fbeta,
                                                  float* __restrict__ out)
{
    int j = blockIdx.x * 256 + threadIdx.x;
    if (j < NDF_) out[j] = (j < A_) ? b_dec[j] : b_fbeta[j - A_];
}

__global__ __launch_bounds__(256) void bcat_kernel(const float* __restrict__ b_ih,
                                                   const float* __restrict__ b_hh,
                                                   float* __restrict__ out)
{
    int j = blockIdx.x * 256 + threadIdx.x;
    if (j < 4 * H_) {
        int srow = (j & 3) * H_ + (j >> 2);
        out[j] = b_ih[srow] + b_hh[srow];
    }
}

__global__ __launch_bounds__(256) void mean_kernel(const short* __restrict__ enc_bf,
                                                   short* __restrict__ meanE_bf)
{
    int g = blockIdx.x * 256 + threadIdx.x;
    int b = g >> 8, cb = g & 255;
    const short* p = enc_bf + (size_t)b * P_ * ENC_ + cb * 8;
    float s[8] = {};
    for (int i = 0; i < P_; i++) {
        bf16x8 v = *(const bf16x8*)(p + (size_t)i * ENC_);
        #pragma unroll
        for (int j = 0; j < 8; j++) s[j] += bf2f(v[j]);
    }
    bf16x8 o;
    #pragma unroll
    for (int j = 0; j < 8; j++) o[j] = f2bf(s[j] * (1.0f / (float)P_));
    *(bf16x8*)(meanE_bf + (size_t)b * ENC_ + cb * 8) = o;
}

__global__ __launch_bounds__(256) void emball_kernel(const int* __restrict__ captions,
                                                     const float* __restrict__ table,
                                                     short* __restrict__ emb_all)
{
    int idx = blockIdx.x * 256 + threadIdx.x;
    int col = idx & 511;
    int bt  = idx >> 9;
    int b   = bt & 127;
    int t   = bt >> 7;
    int tok = captions[b * (T_ + 1) + t];
    emb_all[(size_t)t * B_ * E_ + (size_t)b * E_ + col] = f2bf(table[(size_t)tok * E_ + col]);
}

extern "C" void kernel_launch(void* const* d_in, const int* in_sizes, int n_in,
                              void* d_out, int out_size, void* d_ws, size_t ws_size,
                              hipStream_t stream)
{
    const float* enc      = (const float*)d_in[0];
    const int*   captions = (const int*)  d_in[1];
    const int*   lengths  = (const int*)  d_in[2];
    const float* W_enc    = (const float*)d_in[3];
    const float* b_enc    = (const float*)d_in[4];
    const float* W_dec    = (const float*)d_in[5];
    const float* b_dec    = (const float*)d_in[6];
    const float* w_full   = (const float*)d_in[7];
    const float* emb_tab  = (const float*)d_in[9];
    const float* W_ih     = (const float*)d_in[10];
    const float* b_ih     = (const float*)d_in[11];
    const float* W_hh     = (const float*)d_in[12];
    const float* b_hh     = (const float*)d_in[13];
    const float* W_init_h = (const float*)d_in[14];
    const float* b_init_h = (const float*)d_in[15];
    const float* W_init_c = (const float*)d_in[16];
    const float* b_init_c = (const float*)d_in[17];
    const float* W_fbeta  = (const float*)d_in[18];
    const float* b_fbeta  = (const float*)d_in[19];
    const float* W_fc     = (const float*)d_in[20];
    const float* b_fc     = (const float*)d_in[21];
    float* out = (float*)d_out;

    char* ws = (char*)d_ws;
    size_t off = 0;
    auto alloc = [&](size_t bytes) { void* p = ws + off; off += (bytes + 255) & ~(size_t)255; return p; };
    short* enc_bf   = (short*)alloc((size_t)B_ * P_ * ENC_ * 2);
    short* att1_bf  = (short*)alloc((size_t)B_ * P_ * A_ * 2);
    short* Wenc_bf  = (short*)alloc((size_t)A_ * ENC_ * 2);
    short* Wih_bf   = (short*)alloc((size_t)H_ * ENC_ * 2);
    short* Wic_bf   = (short*)alloc((size_t)H_ * ENC_ * 2);
    short* Wdf_bf   = (short*)alloc((size_t)NDF_ * H_ * 2);
    short* Wcat_bf  = (short*)alloc((size_t)4 * H_ * XK_ * 2);
    short* Wfc_bf   = (short*)alloc((size_t)V_ * H_ * 2);
    float* bdf      = (float*)alloc(NDF_ * 4);
    float* bcat     = (float*)alloc(4 * H_ * 4);
    short* meanE_bf = (short*)alloc((size_t)B_ * ENC_ * 2);
    float* cbuf     = (float*)alloc((size_t)B_ * H_ * 4);
    short* hbufs    = (short*)alloc((size_t)2 * B_ * H_ * 2);
    short* emb_all  = (short*)alloc((size_t)T_ * B_ * E_ * 2);
    short* hn_all   = (short*)alloc((size_t)T_ * B_ * H_ * 2);
    float* attf     = (float*)alloc((size_t)B_ * NDF_ * 4);
    short* ctxbuf   = (short*)alloc((size_t)B_ * ENC_ * 2);
    (void)ws_size;

    // ---- one-time prep
    castenc<<<(B_ * P_ * ENC_) / (256 * 8), 256, 0, stream>>>(enc, enc_bf);
    castk<<<(A_ * ENC_ / 4 + 255) / 256, 256, 0, stream>>>(W_enc, Wenc_bf, A_ * ENC_);
    castk<<<(H_ * ENC_ / 4 + 255) / 256, 256, 0, stream>>>(W_init_h, Wih_bf, H_ * ENC_);
    castk<<<(H_ * ENC_ / 4 + 255) / 256, 256, 0, stream>>>(W_init_c, Wic_bf, H_ * ENC_);
    castk<<<(V_ * H_ / 4 + 255) / 256, 256, 0, stream>>>(W_fc, Wfc_bf, V_ * H_);
    wdf_kernel<<<dim3(H_ / 256, NDF_), 256, 0, stream>>>(W_dec, W_fbeta, Wdf_bf);
    wcat_kernel<<<dim3(XK_ / 256, 4 * H_), 256, 0, stream>>>(W_ih, W_hh, Wcat_bf);
    bdf_kernel<<<(NDF_ + 255) / 256, 256, 0, stream>>>(b_dec, b_fbeta, bdf);
    bcat_kernel<<<(4 * H_ + 255) / 256, 256, 0, stream>>>(b_ih, b_hh, bcat);
    mean_kernel<<<(B_ * ENC_ / 8) / 256, 256, 0, stream>>>(enc_bf, meanE_bf);
    emball_kernel<<<(T_ * B_ * E_) / 256, 256, 0, stream>>>(captions, emb_tab, emb_all);

    // att1 = enc @ W_enc^T + b_enc -> bf16, XCD-grouped
    gemm_bf<<<8 * 8 * ((196 + 7) / 8), 256, 0, stream>>>(
        enc_bf, Wenc_bf, nullptr, att1_bf, b_enc,
        A_, ENC_, ENC_, ENC_, A_, 196, 8, 0, nullptr);
    // h0 -> hbufs[0] (bf16), c0 -> cbuf (fp32)
    gemm_bf<<<H_ / BN, 256, 0, stream>>>(
        meanE_bf, Wih_bf, nullptr, hbufs, b_init_h,
        H_, ENC_, ENC_, ENC_, H_, 1, H_ / BN, 0, nullptr);
    gemm_bf<<<H_ / BN, 256, 0, stream>>>(
        meanE_bf, Wic_bf, cbuf, nullptr, b_init_c,
        H_, ENC_, ENC_, ENC_, H_, 1, H_ / BN, 0, nullptr);

    // ---- the whole T=20 recurrence in one cooperative kernel
    {
        void* kargs[] = {
            (void*)&att1_bf, (void*)&enc_bf, (void*)&Wdf_bf, (void*)&bdf,
            (void*)&w_full, (void*)&emb_all, (void*)&Wcat_bf, (void*)&bcat,
            (void*)&hbufs, (void*)&cbuf, (void*)&hn_all, (void*)&attf,
            (void*)&ctxbuf, (void*)&lengths
        };
        hipError_t cerr = hipLaunchCooperativeKernel(
            (const void*)loop_kernel, dim3(256), dim3(256), kargs, 0, stream);
        if (cerr != hipSuccess) {
            // fallback: per-step launches (same math, same buffers)
            for (int t = 0; t < T_; t++) {
                short* hcur = hbufs + (size_t)(t & 1) * B_ * H_;
                short* hnxt = hbufs + (size_t)((t & 1) ^ 1) * B_ * H_;
                gemm_bf<<<NDF_ / BN, 256, 0, stream>>>(
                    hcur, Wdf_bf, attf, nullptr, bdf,
                    NDF_, H_, H_, H_, NDF_, 1, NDF_ / BN, 0, nullptr);
                esmctx_kernel<<<dim3(2, B_), 256, 0, stream>>>(
                    att1_bf, attf, w_full, enc_bf, ctxbuf, lengths, t);
                gates_lstm<<<(4 * H_) / BN, 256, 0, stream>>>(
                    emb_all + (size_t)t * B_ * E_, ctxbuf, hcur, hnxt, Wcat_bf, bcat,
                    cbuf, hn_all + (size_t)t * B_ * H_, lengths, t);
            }
        }
    }

    // pred: [T*B, V] in one GEMM, remapped to out[b][t][:] with mask
    gemm_bf<<<8 * 157 * (((T_ * B_) / BM + 7) / 8), 256, 0, stream>>>(
        hn_all, Wfc_bf, out, nullptr, b_fc,
        V_, H_, H_, H_, 0, (T_ * B_) / BM, 157, 1, lengths);
}

// Round 6
// 1839.357 us; speedup vs baseline: 3.1727x; 3.1727x over previous
//
#include <hip/hip_runtime.h>
#include <hip/hip_bf16.h>
#include <math.h>

#define B_   128
#define P_   196
#define ENC_ 2048
#define A_   512
#define H_   512
#define E_   512
#define V_   10000
#define T_   20
#define NDF_ 2560   /* fused att2(512) + fbeta(2048) */
#define XK_  3072   /* Wcat K: E + ENC + H */
#define GK_  2560   /* per-step gates K: ENC + H (emb part precomputed) */

typedef __attribute__((ext_vector_type(8))) short bf16x8;
typedef __attribute__((ext_vector_type(4))) short bf16x4;
typedef __attribute__((ext_vector_type(2))) short bf16x2;
typedef __attribute__((ext_vector_type(4))) float f32x4;

__device__ __forceinline__ float sigmoidf_(float x) { return 1.0f / (1.0f + expf(-x)); }

__device__ __forceinline__ short f2bf(float f) {
    unsigned u = __float_as_uint(f);
    u += 0x7fffu + ((u >> 16) & 1u);
    return (short)(u >> 16);
}
__device__ __forceinline__ float bf2f(short s) {
    return __uint_as_float(((unsigned)(unsigned short)s) << 16);
}
__device__ __forceinline__ void gload_lds16(const void* g, void* l) {
    __builtin_amdgcn_global_load_lds(
        (const __attribute__((address_space(1))) void*)g,
        (__attribute__((address_space(3))) void*)l, 16, 0, 0);
}

#define BM 128
#define BN 64
#define BK 64

// shared MFMA inner compute: 64-K slab from As/Bs (XOR-swizzled layout)
#define COMPUTE64(ASP, BSP, CUR)                                               \
    _Pragma("unroll")                                                          \
    for (int kk = 0; kk < BK; kk += 32) {                                      \
        const int kb = (kk >> 3) + (lane >> 4);                                \
        bf16x8 av[4], bv[2];                                                   \
        _Pragma("unroll")                                                      \
        for (int i = 0; i < 4; i++) {                                          \
            int rr = wr * 64 + i * 16 + (lane & 15);                           \
            av[i] = *(const bf16x8*)&(ASP)[(CUR) * (BM * BK) + rr * BK         \
                    + ((kb ^ (rr & 7)) << 3)];                                 \
        }                                                                      \
        _Pragma("unroll")                                                      \
        for (int j = 0; j < 2; j++) {                                          \
            int cc = wc * 32 + j * 16 + (lane & 15);                           \
            bv[j] = *(const bf16x8*)&(BSP)[(CUR) * (BN * BK) + cc * BK         \
                    + ((kb ^ (cc & 7)) << 3)];                                 \
        }                                                                      \
        _Pragma("unroll")                                                      \
        for (int i = 0; i < 4; i++)                                            \
            _Pragma("unroll")                                                  \
            for (int j = 0; j < 2; j++)                                        \
                acc[i][j] = __builtin_amdgcn_mfma_f32_16x16x32_bf16(           \
                    av[i], bv[j], acc[i][j], 0, 0, 0);                         \
    }

// ---------------------------------------------------------------------------
// Generic GEMM: C[M,N] = A_bf16[M,K] @ B_bf16[N,K]^T + bias[N]
// Used for att1 / init / gates_pre / pred.
// pred mode: row r=(t*128+b) -> out[b][t][:], length-masked.
// ---------------------------------------------------------------------------
__global__ __launch_bounds__(256) void gemm_bf(
    const short* __restrict__ A, const short* __restrict__ Bw,
    float* __restrict__ Cf, short* __restrict__ Cb,
    const float* __restrict__ bias,
    int N, int K, int lda, int ldb, int ldc,
    int mtiles, int ntiles, int pred,
    const int* __restrict__ lengths)
{
    __shared__ __attribute__((aligned(16))) short As[2][BM * BK];
    __shared__ __attribute__((aligned(16))) short Bs[2][BN * BK];
    int pm, pn;
    if (mtiles == 1) { pm = 0; pn = blockIdx.x; }
    else {
        int xcd = blockIdx.x & 7, s = blockIdx.x >> 3;
        pn = s % ntiles;
        pm = (s / ntiles) * 8 + xcd;
        if (pm >= mtiles) return;
    }
    const int bm = pm * BM, bn = pn * BN;
    const int tid = threadIdx.x, w = tid >> 6, lane = tid & 63;
    const int wr = w >> 1, wc = w & 1;
    const int lr8 = lane >> 3, lk = lane & 7;

    f32x4 zero4 = {0.f, 0.f, 0.f, 0.f};
    f32x4 acc[4][2];
    #pragma unroll
    for (int i = 0; i < 4; i++)
        #pragma unroll
        for (int j = 0; j < 2; j++) acc[i][j] = zero4;

#define STAGE(buf, k0) {                                                        \
    _Pragma("unroll")                                                           \
    for (int i = 0; i < 4; i++) {                                               \
        int row0 = w * 32 + i * 8; int row = row0 + lr8;                        \
        gload_lds16(A + (size_t)(bm + row) * lda + (k0)                         \
                    + ((lk ^ (row & 7)) << 3), &As[buf][row0 * BK]);            \
    }                                                                           \
    _Pragma("unroll")                                                           \
    for (int i = 0; i < 2; i++) {                                               \
        int row0 = w * 16 + i * 8; int row = row0 + lr8;                        \
        int gn = bn + row; if (gn > N - 1) gn = N - 1;                          \
        gload_lds16(Bw + (size_t)gn * ldb + (k0)                                \
                    + ((lk ^ (row & 7)) << 3), &Bs[buf][row0 * BK]);            \
    } }

    STAGE(0, 0);
    __syncthreads();
    int cur = 0;
    for (int k0 = 0; k0 < K; k0 += BK) {
        if (k0 + BK < K) STAGE(cur ^ 1, k0 + BK);
        COMPUTE64(&As[0][0], &Bs[0][0], cur);
        __syncthreads();
        cur ^= 1;
    }
#undef STAGE

    const int lr = lane >> 4, lc = lane & 15;
    #pragma unroll
    for (int i = 0; i < 4; i++) {
        #pragma unroll
        for (int r = 0; r < 4; r++) {
            int row = bm + wr * 64 + i * 16 + lr * 4 + r;
            #pragma unroll
            for (int j = 0; j < 2; j++) {
                int col = bn + wc * 32 + j * 16 + lc;
                if (col >= N) continue;
                float v = acc[i][j][r] + bias[col];
                if (pred) {
                    int tt = row >> 7, bb = row & 127;
                    float rs = (tt < lengths[bb] - 1) ? 1.0f : 0.0f;
                    Cf[(size_t)bb * T_ * V_ + (size_t)tt * V_ + col] = v * rs;
                } else if (Cb) {
                    Cb[(size_t)row * ldc + col] = f2bf(v);
                } else {
                    Cf[(size_t)row * ldc + col] = v;
                }
            }
        }
    }
}

// ---------------------------------------------------------------------------
// fused e + softmax + context; grid (2, B), 512 threads (8 waves).
// Skips inactive b. alpha stays in LDS; fbeta gate kept in registers.
// ---------------------------------------------------------------------------
__global__ __launch_bounds__(512) void esmctx_kernel(
    const short* __restrict__ att1_bf, const float* __restrict__ attf,
    const float* __restrict__ wfull, const short* __restrict__ enc_bf,
    short* __restrict__ ctxbuf, const int* __restrict__ lengths, int t)
{
    __shared__ float es[P_];
    __shared__ float red[256];
    __shared__ float al[P_];
    __shared__ float sm, ss;
    const int b = blockIdx.y, half = blockIdx.x;
    if (t >= lengths[b] - 1) return;
    const int tid = threadIdx.x, wv = tid >> 6, lane = tid & 63;

    float a2v[8], wv8[8];
    const float* a2 = attf + (size_t)b * NDF_;
    #pragma unroll
    for (int i = 0; i < 8; i++) {
        a2v[i] = a2[lane * 8 + i];
        wv8[i] = wfull[lane * 8 + i];
    }
    // e[row] spread over 8 waves
    for (int row = wv; row < P_; row += 8) {
        bf16x8 a1 = *(const bf16x8*)(att1_bf + ((size_t)b * P_ + row) * A_ + lane * 8);
        float s = 0.0f;
        #pragma unroll
        for (int i = 0; i < 8; i++) {
            float v = bf2f(a1[i]) + a2v[i];
            s += fmaxf(v, 0.0f) * wv8[i];
        }
        #pragma unroll
        for (int off = 32; off > 0; off >>= 1) s += __shfl_down(s, off, 64);
        if (lane == 0) es[row] = s;
    }
    __syncthreads();
    // softmax over 196 (first 256 threads do the tree)
    float v = (tid < P_) ? es[tid] : -1e30f;
    if (tid < 256) red[tid] = v;
    __syncthreads();
    for (int rs = 128; rs > 0; rs >>= 1) {
        if (tid < rs) red[tid] = fmaxf(red[tid], red[tid + rs]);
        __syncthreads();
    }
    if (tid == 0) sm = red[0];
    __syncthreads();
    float ex = (tid < P_) ? expf(v - sm) : 0.0f;
    if (tid < 256) red[tid] = ex;
    __syncthreads();
    for (int rs = 128; rs > 0; rs >>= 1) {
        if (tid < rs) red[tid] += red[tid + rs];
        __syncthreads();
    }
    if (tid == 0) ss = red[0];
    __syncthreads();
    if (tid < P_) al[tid] = ex / ss;
    __syncthreads();

    // context: 2 cols/thread
    const int c0 = half * 1024 + tid * 2;
    const short* eb = enc_bf + (size_t)b * P_ * ENC_ + c0;
    float s0 = 0, s1 = 0;
    for (int p = 0; p < P_; p++) {
        bf16x2 ev = *(const bf16x2*)(eb + (size_t)p * ENC_);
        float a = al[p];
        s0 += a * bf2f(ev[0]); s1 += a * bf2f(ev[1]);
    }
    const float* fb = attf + (size_t)b * NDF_ + A_;
    bf16x2 o;
    o[0] = f2bf(sigmoidf_(fb[c0 + 0]) * s0);
    o[1] = f2bf(sigmoidf_(fb[c0 + 1]) * s1);
    *(bf16x2*)(ctxbuf + (size_t)b * ENC_ + c0) = o;
}

// ---------------------------------------------------------------------------
// gates GEMM [128 x 2048, K=2560 (ctx|h)] + gates_pre(emb@W+b) + LSTM epilogue.
// Wcat rows gate-interleaved (n' = 4*j+g); gpre already contains emb part + bias.
// ---------------------------------------------------------------------------
__global__ __launch_bounds__(256) void gates_lstm(
    const short* __restrict__ ctxbuf, const short* __restrict__ hcur,
    short* __restrict__ hnxt,
    const short* __restrict__ Wcat, const float* __restrict__ gpre,
    float* __restrict__ cbuf, short* __restrict__ hn_t,
    const int* __restrict__ lengths, int t)
{
    __shared__ __attribute__((aligned(16))) char smem[49152];
    short* As0 = (short*)smem;
    short* Bs0 = (short*)(smem + 32768);
    const int bn = blockIdx.x * BN;
    const int tid = threadIdx.x, w = tid >> 6, lane = tid & 63;
    const int wr = w >> 1, wc = w & 1;
    const int lr8 = lane >> 3, lk = lane & 7;

    f32x4 zero4 = {0.f, 0.f, 0.f, 0.f};
    f32x4 acc[4][2];
    #pragma unroll
    for (int i = 0; i < 4; i++)
        #pragma unroll
        for (int j = 0; j < 2; j++) acc[i][j] = zero4;

#define STAGE_G(buf, k0) {                                                      \
    const short* Ap; int Al, kk0;                                               \
    if ((k0) < ENC_) { Ap = ctxbuf; Al = ENC_; kk0 = (k0); }                    \
    else             { Ap = hcur;   Al = H_;   kk0 = (k0) - ENC_; }             \
    _Pragma("unroll")                                                           \
    for (int i = 0; i < 4; i++) {                                               \
        int row0 = w * 32 + i * 8; int row = row0 + lr8;                        \
        gload_lds16(Ap + (size_t)row * Al + kk0 + ((lk ^ (row & 7)) << 3),      \
                    &As0[(buf) * (BM * BK) + row0 * BK]);                       \
    }                                                                           \
    _Pragma("unroll")                                                           \
    for (int i = 0; i < 2; i++) {                                               \
        int row0 = w * 16 + i * 8; int row = row0 + lr8;                        \
        gload_lds16(Wcat + (size_t)(bn + row) * XK_ + E_ + (k0)                 \
                    + ((lk ^ (row & 7)) << 3),                                  \
                    &Bs0[(buf) * (BN * BK) + row0 * BK]);                       \
    } }

    STAGE_G(0, 0);
    __syncthreads();
    int cur = 0;
    for (int k0 = 0; k0 < GK_; k0 += BK) {
        if (k0 + BK < GK_) STAGE_G(cur ^ 1, k0 + BK);
        COMPUTE64(As0, Bs0, cur);
        __syncthreads();
        cur ^= 1;
    }
#undef STAGE_G

    float* gl = (float*)smem;     // 128*68*4 = 34816 B (As/Bs dead)
    const int lr = lane >> 4, lc = lane & 15;
    #pragma unroll
    for (int i = 0; i < 4; i++)
        #pragma unroll
        for (int r = 0; r < 4; r++) {
            int row = wr * 64 + i * 16 + lr * 4 + r;
            #pragma unroll
            for (int j = 0; j < 2; j++) {
                int col = wc * 32 + j * 16 + lc;
                gl[row * 68 + col] = acc[i][j][r] + gpre[(size_t)row * (4 * H_) + bn + col];
            }
        }
    __syncthreads();
    #pragma unroll
    for (int q = 0; q < 8; q++) {
        int id  = tid * 8 + q;
        int row = id >> 4;            // batch b
        int j   = id & 15;            // local hidden unit
        int jg  = (bn >> 2) + j;      // global hidden index
        float i_ = sigmoidf_(gl[row * 68 + 4 * j + 0]);
        float f_ = sigmoidf_(gl[row * 68 + 4 * j + 1]);
        float g_ = tanhf    (gl[row * 68 + 4 * j + 2]);
        float o_ = sigmoidf_(gl[row * 68 + 4 * j + 3]);
        float cn = f_ * cbuf[row * H_ + jg] + i_ * g_;
        float hv = o_ * tanhf(cn);
        hn_t[row * H_ + jg] = f2bf(hv);
        bool m = t < lengths[row] - 1;
        if (m) cbuf[row * H_ + jg] = cn;
        hnxt[row * H_ + jg] = m ? f2bf(hv) : hcur[row * H_ + jg];
    }
}

// ---- one-time prep kernels ------------------------------------------------

__global__ __launch_bounds__(256) void castenc(const float* __restrict__ in,
                                               short* __restrict__ out)
{
    size_t i8 = ((size_t)blockIdx.x * 256 + threadIdx.x) * 8;
    float4 f0 = *(const float4*)(in + i8);
    float4 f1 = *(const float4*)(in + i8 + 4);
    bf16x8 v;
    v[0] = f2bf(f0.x); v[1] = f2bf(f0.y); v[2] = f2bf(f0.z); v[3] = f2bf(f0.w);
    v[4] = f2bf(f1.x); v[5] = f2bf(f1.y); v[6] = f2bf(f1.z); v[7] = f2bf(f1.w);
    *(bf16x8*)(out + i8) = v;
}

__global__ __launch_bounds__(256) void castk(const float* __restrict__ in,
                                             short* __restrict__ out, int n)
{
    int i4 = (blockIdx.x * 256 + threadIdx.x) * 4;
    if (i4 >= n) return;
    float4 f = *(const float4*)(in + i4);
    out[i4 + 0] = f2bf(f.x); out[i4 + 1] = f2bf(f.y);
    out[i4 + 2] = f2bf(f.z); out[i4 + 3] = f2bf(f.w);
}

__global__ __launch_bounds__(256) void wdf_kernel(const float* __restrict__ W_dec,
                                                  const float* __restrict__ W_fbeta,
                                                  short* __restrict__ out)
{
    int k = blockIdx.x * 256 + threadIdx.x;
    int n = blockIdx.y;
    float v = (n < A_) ? W_dec[(size_t)n * H_ + k]
                       : W_fbeta[(size_t)(n - A_) * H_ + k];
    out[(size_t)n * H_ + k] = f2bf(v);
}

// gate-interleaved W_cat: out row n' = 4*j+g  <- source row g*512+j
__global__ __launch_bounds__(256) void wcat_kernel(const float* __restrict__ W_ih,
                                                   const float* __restrict__ W_hh,
                                                   short* __restrict__ out)
{
    int k = blockIdx.x * 256 + threadIdx.x;
    int n = blockIdx.y;
    int srow = (n & 3) * H_ + (n >> 2);
    float v = (k < E_ + ENC_) ? W_ih[(size_t)srow * (E_ + ENC_) + k]
                              : W_hh[(size_t)srow * H_ + (k - (E_ + ENC_))];
    out[(size_t)n * XK_ + k] = f2bf(v);
}

__global__ __launch_bounds__(256) void bdf_kernel(const float* __restrict__ b_dec,
                                                  const float* __restrict__ b_fbeta,
                                                  float* __restrict__ out)
{
    int j = blockIdx.x * 256 + threadIdx.x;
    if (j < NDF_) out[j] = (j < A_) ? b_dec[j] : b_fbeta[j - A_];
}

__global__ __launch_bounds__(256) void bcat_kernel(const float* __restrict__ b_ih,
                                                   const float* __restrict__ b_hh,
                                                   float* __restrict__ out)
{
    int j = blockIdx.x * 256 + threadIdx.x;   // interleaved index
    if (j < 4 * H_) {
        int srow = (j & 3) * H_ + (j >> 2);
        out[j] = b_ih[srow] + b_hh[srow];
    }
}

__global__ __launch_bounds__(256) void mean_kernel(const short* __restrict__ enc_bf,
                                                   short* __restrict__ meanE_bf)
{
    int g = blockIdx.x * 256 + threadIdx.x;
    int b = g >> 8, cb = g & 255;
    const short* p = enc_bf + (size_t)b * P_ * ENC_ + cb * 8;
    float s[8] = {};
    for (int i = 0; i < P_; i++) {
        bf16x8 v = *(const bf16x8*)(p + (size_t)i * ENC_);
        #pragma unroll
        for (int j = 0; j < 8; j++) s[j] += bf2f(v[j]);
    }
    bf16x8 o;
    #pragma unroll
    for (int j = 0; j < 8; j++) o[j] = f2bf(s[j] * (1.0f / (float)P_));
    *(bf16x8*)(meanE_bf + (size_t)b * ENC_ + cb * 8) = o;
}

__global__ __launch_bounds__(256) void emball_kernel(const int* __restrict__ captions,
                                                     const float* __restrict__ table,
                                                     short* __restrict__ emb_all)
{
    int idx = blockIdx.x * 256 + threadIdx.x;
    int col = idx & 511;
    int bt  = idx >> 9;
    int b   = bt & 127;
    int t   = bt >> 7;
    int tok = captions[b * (T_ + 1) + t];
    emb_all[(size_t)t * B_ * E_ + (size_t)b * E_ + col] = f2bf(table[(size_t)tok * E_ + col]);
}

extern "C" void kernel_launch(void* const* d_in, const int* in_sizes, int n_in,
                              void* d_out, int out_size, void* d_ws, size_t ws_size,
                              hipStream_t stream)
{
    const float* enc      = (const float*)d_in[0];
    const int*   captions = (const int*)  d_in[1];
    const int*   lengths  = (const int*)  d_in[2];
    const float* W_enc    = (const float*)d_in[3];
    const float* b_enc    = (const float*)d_in[4];
    const float* W_dec    = (const float*)d_in[5];
    const float* b_dec    = (const float*)d_in[6];
    const float* w_full   = (const float*)d_in[7];
    const float* emb_tab  = (const float*)d_in[9];
    const float* W_ih     = (const float*)d_in[10];
    const float* b_ih     = (const float*)d_in[11];
    const float* W_hh     = (const float*)d_in[12];
    const float* b_hh     = (const float*)d_in[13];
    const float* W_init_h = (const float*)d_in[14];
    const float* b_init_h = (const float*)d_in[15];
    const float* W_init_c = (const float*)d_in[16];
    const float* b_init_c = (const float*)d_in[17];
    const float* W_fbeta  = (const float*)d_in[18];
    const float* b_fbeta  = (const float*)d_in[19];
    const float* W_fc     = (const float*)d_in[20];
    const float* b_fc     = (const float*)d_in[21];
    float* out = (float*)d_out;

    char* ws = (char*)d_ws;
    size_t off = 0;
    auto alloc = [&](size_t bytes) { void* p = ws + off; off += (bytes + 255) & ~(size_t)255; return p; };
    short* enc_bf    = (short*)alloc((size_t)B_ * P_ * ENC_ * 2);
    short* att1_bf   = (short*)alloc((size_t)B_ * P_ * A_ * 2);
    short* Wenc_bf   = (short*)alloc((size_t)A_ * ENC_ * 2);
    short* Wih_bf    = (short*)alloc((size_t)H_ * ENC_ * 2);
    short* Wic_bf    = (short*)alloc((size_t)H_ * ENC_ * 2);
    short* Wdf_bf    = (short*)alloc((size_t)NDF_ * H_ * 2);
    short* Wcat_bf   = (short*)alloc((size_t)4 * H_ * XK_ * 2);
    short* Wfc_bf    = (short*)alloc((size_t)V_ * H_ * 2);
    float* bdf       = (float*)alloc(NDF_ * 4);
    float* bcat      = (float*)alloc(4 * H_ * 4);
    short* meanE_bf  = (short*)alloc((size_t)B_ * ENC_ * 2);
    float* cbuf      = (float*)alloc((size_t)B_ * H_ * 4);
    short* hbufs     = (short*)alloc((size_t)2 * B_ * H_ * 2);
    short* emb_all   = (short*)alloc((size_t)T_ * B_ * E_ * 2);
    short* hn_all    = (short*)alloc((size_t)T_ * B_ * H_ * 2);
    float* attf      = (float*)alloc((size_t)B_ * NDF_ * 4);
    short* ctxbuf    = (short*)alloc((size_t)B_ * ENC_ * 2);
    float* gates_pre = (float*)alloc((size_t)T_ * B_ * 4 * H_ * 4);  // 21 MB
    (void)ws_size;

    // ---- one-time prep
    castenc<<<(B_ * P_ * ENC_) / (256 * 8), 256, 0, stream>>>(enc, enc_bf);
    castk<<<(A_ * ENC_ / 4 + 255) / 256, 256, 0, stream>>>(W_enc, Wenc_bf, A_ * ENC_);
    castk<<<(H_ * ENC_ / 4 + 255) / 256, 256, 0, stream>>>(W_init_h, Wih_bf, H_ * ENC_);
    castk<<<(H_ * ENC_ / 4 + 255) / 256, 256, 0, stream>>>(W_init_c, Wic_bf, H_ * ENC_);
    castk<<<(V_ * H_ / 4 + 255) / 256, 256, 0, stream>>>(W_fc, Wfc_bf, V_ * H_);
    wdf_kernel<<<dim3(H_ / 256, NDF_), 256, 0, stream>>>(W_dec, W_fbeta, Wdf_bf);
    wcat_kernel<<<dim3(XK_ / 256, 4 * H_), 256, 0, stream>>>(W_ih, W_hh, Wcat_bf);
    bdf_kernel<<<(NDF_ + 255) / 256, 256, 0, stream>>>(b_dec, b_fbeta, bdf);
    bcat_kernel<<<(4 * H_ + 255) / 256, 256, 0, stream>>>(b_ih, b_hh, bcat);
    mean_kernel<<<(B_ * ENC_ / 8) / 256, 256, 0, stream>>>(enc_bf, meanE_bf);
    emball_kernel<<<(T_ * B_ * E_) / 256, 256, 0, stream>>>(captions, emb_tab, emb_all);

    // att1 = enc @ W_enc^T + b_enc -> bf16, XCD-grouped
    gemm_bf<<<8 * 8 * ((196 + 7) / 8), 256, 0, stream>>>(
        enc_bf, Wenc_bf, nullptr, att1_bf, b_enc,
        A_, ENC_, ENC_, ENC_, A_, 196, 8, 0, nullptr);
    // gates_pre[T*B, 2048] = emb_all @ Wcat[:, :512]^T + bcat  (fp32)
    gemm_bf<<<8 * 32 * (((T_ * B_) / BM + 7) / 8), 256, 0, stream>>>(
        emb_all, Wcat_bf, gates_pre, nullptr, bcat,
        4 * H_, E_, E_, XK_, 4 * H_, (T_ * B_) / BM, 32, 0, nullptr);
    // h0 -> hbufs[0] (bf16), c0 -> cbuf (fp32)
    gemm_bf<<<H_ / BN, 256, 0, stream>>>(
        meanE_bf, Wih_bf, nullptr, hbufs, b_init_h,
        H_, ENC_, ENC_, ENC_, H_, 1, H_ / BN, 0, nullptr);
    gemm_bf<<<H_ / BN, 256, 0, stream>>>(
        meanE_bf, Wic_bf, cbuf, nullptr, b_init_c,
        H_, ENC_, ENC_, ENC_, H_, 1, H_ / BN, 0, nullptr);

    for (int t = 0; t < T_; t++) {
        short* hcur = hbufs + (size_t)(t & 1) * B_ * H_;
        short* hnxt = hbufs + (size_t)((t & 1) ^ 1) * B_ * H_;
        // attf = h @ [W_dec|W_fbeta]^T + [b_dec|b_fbeta]
        gemm_bf<<<NDF_ / BN, 256, 0, stream>>>(
            hcur, Wdf_bf, attf, nullptr, bdf,
            NDF_, H_, H_, H_, NDF_, 1, NDF_ / BN, 0, nullptr);
        esmctx_kernel<<<dim3(2, B_), 512, 0, stream>>>(
            att1_bf, attf, w_full, enc_bf, ctxbuf, lengths, t);
        gates_lstm<<<(4 * H_) / BN, 256, 0, stream>>>(
            ctxbuf, hcur, hnxt, Wcat_bf, gates_pre + (size_t)t * B_ * 4 * H_,
            cbuf, hn_all + (size_t)t * B_ * H_, lengths, t);
    }
    // pred: [T*B, V] in one GEMM, remapped to out[b][t][:] with mask
    gemm_bf<<<8 * 157 * (((T_ * B_) / BM + 7) / 8), 256, 0, stream>>>(
        hn_all, Wfc_bf, out, nullptr, b_fc,
        V_, H_, H_, H_, 0, (T_ * B_) / BM, 157, 1, lengths);
}